// Round 2
// baseline (83.461 us; speedup 1.0000x reference)
//
#include <hip/hip_runtime.h>

// OsuRatingSystem: out[b] = dot(player_table[pidx[b]], map_table[midx[b]]), D=64.
// Memory-bound random gather. 16 lanes per sample, one float4 per lane.
// Cache policy: player table (256 MB, ~1x use) + indices + output are
// NON-TEMPORAL (evict-first) so L2/L3 retain the map table (51 MB, ~5x reuse).

typedef float f4 __attribute__((ext_vector_type(4)));

__global__ __launch_bounds__(256) void osu_rating_dot_kernel(
    const int* __restrict__ pidx,
    const int* __restrict__ midx,
    const float* __restrict__ ptab,
    const float* __restrict__ mtab,
    float* __restrict__ out,
    int n)
{
    int tid = blockIdx.x * blockDim.x + threadIdx.x;
    int sample = tid >> 4;   // 16 lanes per sample
    int lane4  = tid & 15;   // which float4 of the 64-float row
    if (sample >= n) return;

    int pi = __builtin_nontemporal_load(pidx + sample);
    int mi = __builtin_nontemporal_load(midx + sample);

    // Player row: streaming, evict-first.
    const f4* pp = reinterpret_cast<const f4*>(ptab + (size_t)pi * 64 + (size_t)lane4 * 4);
    f4 pv = __builtin_nontemporal_load(pp);

    // Map row: hot (5x average reuse) -> normal cached load.
    const f4* mp = reinterpret_cast<const f4*>(mtab + (size_t)mi * 64 + (size_t)lane4 * 4);
    f4 mv = *mp;

    float s = pv.x * mv.x + pv.y * mv.y + pv.z * mv.z + pv.w * mv.w;

    // Reduce across the 16 lanes of this sample's group.
    s += __shfl_xor(s, 1, 16);
    s += __shfl_xor(s, 2, 16);
    s += __shfl_xor(s, 4, 16);
    s += __shfl_xor(s, 8, 16);

    if (lane4 == 0) __builtin_nontemporal_store(s, out + sample);
}

extern "C" void kernel_launch(void* const* d_in, const int* in_sizes, int n_in,
                              void* d_out, int out_size, void* d_ws, size_t ws_size,
                              hipStream_t stream) {
    const int*   pidx = (const int*)d_in[0];
    const int*   midx = (const int*)d_in[1];
    const float* ptab = (const float*)d_in[2];
    const float* mtab = (const float*)d_in[3];
    float*       out  = (float*)d_out;

    int n = in_sizes[0];              // BATCH = 1,000,000
    int total_threads = n * 16;       // 16 lanes per sample
    int block = 256;
    int grid = (total_threads + block - 1) / block;

    osu_rating_dot_kernel<<<grid, block, 0, stream>>>(pidx, midx, ptab, mtab, out, n);
}